// Round 5
// baseline (328.626 us; speedup 1.0000x reference)
//
#include <hip/hip_runtime.h>
#include <stdint.h>

typedef __bf16 bf16_t;
typedef __bf16 bf16x4 __attribute__((ext_vector_type(4)));
typedef __bf16 bf16x8 __attribute__((ext_vector_type(8)));
typedef float  f32x4  __attribute__((ext_vector_type(4)));
typedef float  f32x16 __attribute__((ext_vector_type(16)));

#define BB   4
#define SS   2048
#define DD   1024
#define HH   16
#define DH   64

#if __has_builtin(__builtin_amdgcn_exp2f)
#define EXP2F(x) __builtin_amdgcn_exp2f(x)
#else
#define EXP2F(x) __expf((x) * 0.6931471805599453f)
#endif

// ---------------------------------------------------------------- helpers
__device__ __forceinline__ void gload_lds16(const void* g, void* l) {
    // dest LDS addr = wave-uniform base + lane*16 (measured m104/m108)
    __builtin_amdgcn_global_load_lds(
        (__attribute__((address_space(1))) void*)(uintptr_t)g,
        (__attribute__((address_space(3))) void*)(uint32_t)(uintptr_t)l,
        16, 0, 0);
}

// ---------------------------------------------------------------- fp32 -> bf16 converts
__global__ __launch_bounds__(256) void cvt_kernel(const float* __restrict__ src,
                                                  bf16_t* __restrict__ dst, int n4) {
    int i = blockIdx.x * 256 + threadIdx.x;
    if (i < n4) {
        float4 v = ((const float4*)src)[i];
        bf16x4 o;
        o.x = (bf16_t)v.x; o.y = (bf16_t)v.y; o.z = (bf16_t)v.z; o.w = (bf16_t)v.w;
        ((bf16x4*)dst)[i] = o;
    }
}

// all four weight matrices in one launch (each 1024x1024 fp32 = 262144 float4)
__global__ __launch_bounds__(256) void cvt_weights(const float* __restrict__ Wq,
                                                   const float* __restrict__ Wk,
                                                   const float* __restrict__ Wv,
                                                   const float* __restrict__ Wo,
                                                   bf16_t* __restrict__ Wqkv,
                                                   bf16_t* __restrict__ Wob) {
    int i = blockIdx.x * 256 + threadIdx.x;      // 0 .. 4*262144
    int which = i >> 18, p = i & 262143;
    const float* src = (which == 0) ? Wq : (which == 1) ? Wk : (which == 2) ? Wv : Wo;
    bf16_t* dst = (which < 3) ? (Wqkv + (long)which * 1048576) : Wob;
    float4 v = ((const float4*)src)[p];
    bf16x4 o;
    o.x = (bf16_t)v.x; o.y = (bf16_t)v.y; o.z = (bf16_t)v.z; o.w = (bf16_t)v.w;
    ((bf16x4*)dst)[p] = o;
}

__global__ __launch_bounds__(256) void pack_bias(const float* __restrict__ bq,
                                                 const float* __restrict__ bk,
                                                 const float* __restrict__ bv,
                                                 float* __restrict__ bqkv) {
    int i = blockIdx.x * 256 + threadIdx.x;
    if (i < 3072)
        bqkv[i] = (i < 1024) ? bq[i] : ((i < 2048) ? bk[i - 1024] : bv[i - 2048]);
}

// cos/sin table: tab[s*512 + pr] = {cos(s*invf), sin(s*invf)}, invf = 10000^(-2pr/1024)
__global__ __launch_bounds__(256) void rope_tab(float2* __restrict__ tab) {
    int i = blockIdx.x * 256 + threadIdx.x;      // 2048*512
    int s = i >> 9, pr = i & 511;
    float inv = powf(10000.0f, -(float)(2 * pr) * (1.0f / 1024.0f));
    float c, sn;
    sincosf((float)s * inv, &sn, &c);
    tab[i] = make_float2(c, sn);
}

// ---------------------------------------------------------------- fused QKV GEMM + bias + RoPE
__global__ __launch_bounds__(256, 2) void gemm_qkv_rope(
        const bf16_t* __restrict__ A, const bf16_t* __restrict__ Bm,
        const float* __restrict__ bias, const float2* __restrict__ tab,
        bf16_t* __restrict__ Qb, bf16_t* __restrict__ Kb, bf16_t* __restrict__ Vtmp)
{
    __shared__ __attribute__((aligned(16))) bf16_t As[128 * 32];
    __shared__ __attribute__((aligned(16))) bf16_t Bs[128 * 32];
    const int t = threadIdx.x;
    const int lane = t & 63, w = t >> 6;
    const int wm = w >> 1, wn = w & 1;
    const int l15 = lane & 15, l4 = lane >> 4;
    const long rowA0 = (long)blockIdx.x * 128;
    const long rowB0 = (long)blockIdx.y * 128;
    const int K = 1024, N = 1024;  // per-part N

    const f32x4 vz = {0.f, 0.f, 0.f, 0.f};
    f32x4 acc[4][4];
#pragma unroll
    for (int i = 0; i < 4; ++i)
#pragma unroll
        for (int j = 0; j < 4; ++j) acc[i][j] = vz;

    for (int kk = 0; kk < K; kk += 32) {
        __syncthreads();
#pragma unroll
        for (int i = 0; i < 2; ++i) {
            const int cb = i * 256 + w * 64;
            const int c  = cb + lane;
            const int r  = c >> 2;
            const int ko = (c & 3) << 3;
            gload_lds16(A  + (rowA0 + r) * K + kk + ko, As + cb * 8);
            gload_lds16(Bm + (rowB0 + r) * K + kk + ko, Bs + cb * 8);
        }
        __syncthreads();
        bf16x8 af[4], bfr[4];
#pragma unroll
        for (int i = 0; i < 4; ++i)
            af[i] = *(const bf16x8*)(As + (wm * 64 + i * 16 + l15) * 32 + l4 * 8);
#pragma unroll
        for (int j = 0; j < 4; ++j)
            bfr[j] = *(const bf16x8*)(Bs + (wn * 64 + j * 16 + l15) * 32 + l4 * 8);
#pragma unroll
        for (int i = 0; i < 4; ++i)
#pragma unroll
            for (int j = 0; j < 4; ++j)
                acc[i][j] = __builtin_amdgcn_mfma_f32_16x16x32_bf16(af[i], bfr[j], acc[i][j], 0, 0, 0);
    }

    const long crow0 = rowA0 + wm * 64;
    const int  ccol0 = (int)rowB0 + wn * 64;     // global col in [0,3072), multiple of 64
    const int  part  = blockIdx.y >> 3;          // 0=Q, 1=K, 2=V

    if (part == 2) {
#pragma unroll
        for (int i = 0; i < 4; ++i) {
#pragma unroll
            for (int j = 0; j < 4; ++j) {
                const int col = ccol0 + j * 16 + l15;
                const float bb = bias[col];
                const int vc = col - 2048;
#pragma unroll
                for (int r = 0; r < 4; ++r) {
                    const long row = crow0 + i * 16 + l4 * 4 + r;
                    Vtmp[row * N + vc] = (bf16_t)(acc[i][j][r] + bb);
                }
            }
        }
    } else {
        bf16_t* dst0 = part ? Kb : Qb;
        const int h = (ccol0 & 1023) >> 6;       // this wave's 64-col strip = one head
#pragma unroll
        for (int i = 0; i < 4; ++i) {
#pragma unroll
            for (int j = 0; j < 4; ++j) {
                const int col = ccol0 + j * 16 + l15;
                const float bb = bias[col];
                const int even = !(col & 1);
                const int dd = j * 16 + l15;
                const float2* trow = tab + (col >> 1 & 511);
#pragma unroll
                for (int r = 0; r < 4; ++r) {
                    const long row = crow0 + i * 16 + l4 * 4 + r;
                    const int b = (int)(row >> 11), s = (int)(row & 2047);
                    const float val = acc[i][j][r] + bb;
                    const float par = __shfl_xor(val, 1);
                    const float2 cs = trow[s * 512];
                    const float out = even ? (val * cs.x - par * cs.y)
                                           : fmaf(val, cs.x, par * cs.y);
                    dst0[((long)((b * HH + h) * SS + s)) * DH + dd] = (bf16_t)out;
                }
            }
        }
    }
}

// ---------------------------------------------------------------- NT GEMM (output projection)
template <int OUT_BF16>
__global__ __launch_bounds__(256, 2) void gemm_bt(
        const bf16_t* __restrict__ A, const bf16_t* __restrict__ Bm,
        const float* __restrict__ bias, void* __restrict__ Cout,
        int M, int N, int K)
{
    __shared__ __attribute__((aligned(16))) bf16_t As[128 * 32];
    __shared__ __attribute__((aligned(16))) bf16_t Bs[128 * 32];
    const int t = threadIdx.x;
    const int lane = t & 63, w = t >> 6;
    const int wm = w >> 1, wn = w & 1;
    const int l15 = lane & 15, l4 = lane >> 4;
    const long rowA0 = (long)blockIdx.x * 128;
    const long rowB0 = (long)blockIdx.y * 128;

    const f32x4 vz = {0.f, 0.f, 0.f, 0.f};
    f32x4 acc[4][4];
#pragma unroll
    for (int i = 0; i < 4; ++i)
#pragma unroll
        for (int j = 0; j < 4; ++j) acc[i][j] = vz;

    for (int kk = 0; kk < K; kk += 32) {
        __syncthreads();
#pragma unroll
        for (int i = 0; i < 2; ++i) {
            const int cb = i * 256 + w * 64;
            const int c  = cb + lane;
            const int r  = c >> 2;
            const int ko = (c & 3) << 3;
            gload_lds16(A  + (rowA0 + r) * K + kk + ko, As + cb * 8);
            gload_lds16(Bm + (rowB0 + r) * K + kk + ko, Bs + cb * 8);
        }
        __syncthreads();
        bf16x8 af[4], bfr[4];
#pragma unroll
        for (int i = 0; i < 4; ++i)
            af[i] = *(const bf16x8*)(As + (wm * 64 + i * 16 + l15) * 32 + l4 * 8);
#pragma unroll
        for (int j = 0; j < 4; ++j)
            bfr[j] = *(const bf16x8*)(Bs + (wn * 64 + j * 16 + l15) * 32 + l4 * 8);
#pragma unroll
        for (int i = 0; i < 4; ++i)
#pragma unroll
            for (int j = 0; j < 4; ++j)
                acc[i][j] = __builtin_amdgcn_mfma_f32_16x16x32_bf16(af[i], bfr[j], acc[i][j], 0, 0, 0);
    }

    const long crow0 = rowA0 + wm * 64;
    const int  ccol0 = (int)rowB0 + wn * 64;
#pragma unroll
    for (int i = 0; i < 4; ++i) {
#pragma unroll
        for (int j = 0; j < 4; ++j) {
            const int col = ccol0 + j * 16 + l15;
            const float bb = bias[col];
#pragma unroll
            for (int r = 0; r < 4; ++r) {
                const long row = crow0 + i * 16 + l4 * 4 + r;
                const float v = acc[i][j][r] + bb;
                if (OUT_BF16) ((bf16_t*)Cout)[row * N + col] = (bf16_t)v;
                else          ((float*)Cout)[row * N + col]  = v;
            }
        }
    }
}

// ---------------------------------------------------------------- V transpose repack
// Vtmp (n, h*64+d) -> Vt (b*H+h, dh, s) bf16
__global__ __launch_bounds__(256) void repack_v(const bf16_t* __restrict__ Vtmp,
                                                bf16_t* __restrict__ Vt)
{
    __shared__ bf16_t tile[64][65];
    const int t = threadIdx.x;
    const int st = blockIdx.x, bh = blockIdx.y;
    const int b = bh >> 4, h = bh & 15;
    const long nbase = (long)b * SS + st * 64;
#pragma unroll
    for (int e = 0; e < 16; ++e) {
        const int i = e * 256 + t;
        const int r = i >> 6, d = i & 63;
        tile[r][d] = Vtmp[(nbase + r) * 1024 + h * 64 + d];
    }
    __syncthreads();
#pragma unroll
    for (int e = 0; e < 16; ++e) {
        const int i = e * 256 + t;
        const int d = i >> 6, s = i & 63;
        Vt[((long)bh * DH + d) * SS + st * 64 + s] = tile[s][d];
    }
}

// ---------------------------------------------------------------- flash attention
// grid (16 q-tiles of 128, 64 bh). 4 waves; wave w owns q rows [qt*128+32w, +32).
//
// R5: no P LDS round-trip. Compute S^T (C-layout: col=q=l31, row=key), then
// PV as O^T = V^T * P^T with P^T as the B operand. B-frag layout
// (n=lane&31, k=(lane>>5)*8+j) is reached from S^T C-layout by exchanging
// register quads with lane^32: B-frag(m): s=m>>1, g0=2(m&1)+hl;
//   elems 0-3 = quad g0 of hl=0 lane, elems 4-7 = quad g0 of hl=1 lane.
// Per wave-iter: 8 K + 8 V b128 reads (octet-clean swizzle), 0 LDS writes,
// 16 dword shuffles, ONE barrier. DMA double-buffered: stage(kt+1) issued
// right after the barrier, drains during compute -> hidden.
// Epilogue: O^T -> LDS (pitch 68: 2-way max, 8B-aligned rows) -> coalesced
// dwordx4 global stores. invq is per-lane uniform (col=q) -> no lbuf.
__global__ __launch_bounds__(256) void attn_kernel(const bf16_t* __restrict__ Qb,
                                                   const bf16_t* __restrict__ Kb,
                                                   const bf16_t* __restrict__ Vt,
                                                   bf16_t* __restrict__ Ob)
{
    __shared__ __attribute__((aligned(16))) bf16_t KV[2][2][64 * 64]; // [buf][K/V]
    const int t = threadIdx.x, lane = t & 63, w = t >> 6;
    const int l31 = lane & 31, hl = lane >> 5;
    const int qt = blockIdx.x, bh = blockIdx.y;
    const bf16_t* Qbh = Qb + (long)bh * SS * DH;
    const bf16_t* Kbh = Kb + (long)bh * SS * DH;
    const bf16_t* Vbh = Vt + (long)bh * DH * SS;

    // Q B-frags: qf[c][j] = Q[q = qrow][d = 16c + 8hl + j]
    const long qrow = (long)qt * 128 + w * 32 + l31;
    bf16x8 qf[4];
#pragma unroll
    for (int c = 0; c < 4; ++c)
        qf[c] = *(const bf16x8*)(Qbh + qrow * DH + 16 * c + 8 * hl);

    f32x16 oacc0, oacc1;
#pragma unroll
    for (int e = 0; e < 16; ++e) { oacc0[e] = 0.f; oacc1[e] = 0.f; }
    float l_sum = 0.f;

    // staging: lane handles chunks L = i*256 + w*64 + lane (i=0,1) per tile;
    // row = L>>3, swizzled src chunk = (L&7)^(row&7)
    int srow[2], scc[2];
#pragma unroll
    for (int i = 0; i < 2; ++i) {
        const int L = i * 256 + w * 64 + lane;
        srow[i] = L >> 3;
        scc[i]  = (L & 7) ^ (srow[i] & 7);
    }

    const float SC = 0.125f * 1.4426950408889634f;
    const float BI = -8.0f  * 1.4426950408889634f;
    const int xk = l31 & 7;   // read swizzle: rows s*32+l31 / t2*32+l31 have row&7 = l31&7

    // prologue: stage tile 0 into buf 0
    {
        const bf16_t* Ksrc = Kbh;
#pragma unroll
        for (int i = 0; i < 2; ++i) {
            const int cb = i * 256 + w * 64;
            gload_lds16(Ksrc + srow[i] * 64 + scc[i] * 8, &KV[0][0][cb * 8]);
            gload_lds16(Vbh + (long)srow[i] * SS + scc[i] * 8, &KV[0][1][cb * 8]);
        }
    }

    for (int kt = 0; kt < SS / 64; ++kt) {
        const int nb = kt & 1;
        __syncthreads();                  // drains DMA of tile kt; prev reads done
        if (kt + 1 < SS / 64) {           // stage kt+1 into other buffer (hidden)
            const bf16_t* Ksrc = Kbh + (long)(kt + 1) * 64 * DH;
#pragma unroll
            for (int i = 0; i < 2; ++i) {
                const int cb = i * 256 + w * 64;
                gload_lds16(Ksrc + srow[i] * 64 + scc[i] * 8, &KV[nb ^ 1][0][cb * 8]);
                gload_lds16(Vbh + (long)srow[i] * SS + (kt + 1) * 64 + scc[i] * 8,
                            &KV[nb ^ 1][1][cb * 8]);
            }
        }
        const bf16_t* Ks = KV[nb][0];
        const bf16_t* Vs = KV[nb][1];

        // S^T strips + exp + pack into quads (own[s][g] = keys 8g+4hl+0..3)
        uint2 own[2][4], prt[2][4];
#pragma unroll
        for (int s = 0; s < 2; ++s) {
            f32x16 sacc;
#pragma unroll
            for (int e = 0; e < 16; ++e) sacc[e] = 0.f;
#pragma unroll
            for (int c = 0; c < 4; ++c) {
                const bf16x8 af = *(const bf16x8*)(Ks + (s * 32 + l31) * 64 +
                                                   (((2 * c + hl) ^ xk) << 3));
                sacc = __builtin_amdgcn_mfma_f32_32x32x16_bf16(af, qf[c], sacc, 0, 0, 0);
            }
#pragma unroll
            for (int g = 0; g < 4; ++g) {
                union { bf16_t h[2]; unsigned int u; } u0, u1;
                const float p0 = EXP2F(fmaf(sacc[4 * g + 0], SC, BI));
                const float p1 = EXP2F(fmaf(sacc[4 * g + 1], SC, BI));
                const float p2 = EXP2F(fmaf(sacc[4 * g + 2], SC, BI));
                const float p3 = EXP2F(fmaf(sacc[4 * g + 3], SC, BI));
                u0.h[0] = (bf16_t)p0; u0.h[1] = (bf16_t)p1;
                u1.h[0] = (bf16_t)p2; u1.h[1] = (bf16_t)p3;
                // sum the ROUNDED values so l matches P exactly
                l_sum += ((float)u0.h[0] + (float)u0.h[1]) +
                         ((float)u1.h[0] + (float)u1.h[1]);
                own[s][g].x = u0.u; own[s][g].y = u1.u;
            }
        }
#pragma unroll
        for (int s = 0; s < 2; ++s)
#pragma unroll
            for (int g = 0; g < 4; ++g) {
                prt[s][g].x = (unsigned int)__shfl_xor((int)own[s][g].x, 32);
                prt[s][g].y = (unsigned int)__shfl_xor((int)own[s][g].y, 32);
            }

        // PV: O^T[d][q] += V^T[d][k] P^T[k][q]
#pragma unroll
        for (int m = 0; m < 4; ++m) {
            const int s = m >> 1, ge = 2 * (m & 1);
            union { unsigned int u[4]; bf16x8 v; } pf;
            pf.u[0] = hl ? prt[s][ge + 1].x : own[s][ge].x;
            pf.u[1] = hl ? prt[s][ge + 1].y : own[s][ge].y;
            pf.u[2] = hl ? own[s][ge + 1].x : prt[s][ge].x;
            pf.u[3] = hl ? own[s][ge + 1].y : prt[s][ge].y;
            const int co = ((2 * m + hl) ^ xk) << 3;
            const bf16x8 vf0 = *(const bf16x8*)(Vs + l31 * 64 + co);
            const bf16x8 vf1 = *(const bf16x8*)(Vs + (32 + l31) * 64 + co);
            oacc0 = __builtin_amdgcn_mfma_f32_32x32x16_bf16(vf0, pf.v, oacc0, 0, 0, 0);
            oacc1 = __builtin_amdgcn_mfma_f32_32x32x16_bf16(vf1, pf.v, oacc1, 0, 0, 0);
        }
    }

    // denominator: lane covers half the keys of its q-col; partner has the rest
    const float lt = l_sum + __shfl_xor(l_sum, 32);
    const float invq = 1.0f / lt;

    // epilogue: O^T -> per-wave LDS strip (pitch 68) -> coalesced global
    __syncthreads();                       // all waves done reading KV
    bf16_t* So = (bf16_t*)KV + w * (32 * 68);
#pragma unroll
    for (int t2 = 0; t2 < 2; ++t2) {
#pragma unroll
        for (int g = 0; g < 4; ++g) {
            const int d0 = t2 * 32 + 8 * g + 4 * hl;
            union { bf16_t h[2]; unsigned int u; } a, bq;
            const f32x16& oa = t2 ? oacc1 : oacc0;
            a.h[0]  = (bf16_t)(oa[4 * g + 0] * invq);
            a.h[1]  = (bf16_t)(oa[4 * g + 1] * invq);
            bq.h[0] = (bf16_t)(oa[4 * g + 2] * invq);
            bq.h[1] = (bf16_t)(oa[4 * g + 3] * invq);
            *(unsigned int*)(So + l31 * 68 + d0)     = a.u;
            *(unsigned int*)(So + l31 * 68 + d0 + 2) = bq.u;
        }
    }
    // wave-local: in-wave DS ops are ordered; read back coalesced
    const int b = bh >> 4, h = bh & 15;
    const long orow0 = (long)b * SS + qt * 128 + w * 32;
#pragma unroll
    for (int p = 0; p < 4; ++p) {
        const int qr = p * 8 + (lane >> 3);
        const int d0 = (lane & 7) * 8;
        const uint2 lo = *(const uint2*)(So + qr * 68 + d0);      // 8B-aligned
        const uint2 hi = *(const uint2*)(So + qr * 68 + d0 + 4);
        uint4 val; val.x = lo.x; val.y = lo.y; val.z = hi.x; val.w = hi.y;
        *(uint4*)(Ob + (orow0 + qr) * DD + h * DH + d0) = val;
    }
}

// ---------------------------------------------------------------- launch
extern "C" void kernel_launch(void* const* d_in, const int* in_sizes, int n_in,
                              void* d_out, int out_size, void* d_ws, size_t ws_size,
                              hipStream_t stream)
{
    const float* queries = (const float*)d_in[0];
    const float* Wq = (const float*)d_in[1];
    const float* bq = (const float*)d_in[2];
    const float* Wk = (const float*)d_in[3];
    const float* bk = (const float*)d_in[4];
    const float* Wv = (const float*)d_in[5];
    const float* bv = (const float*)d_in[6];
    const float* Wo = (const float*)d_in[7];
    const float* bo = (const float*)d_in[8];

    char* ws = (char*)d_ws;
    size_t off = 0;
    auto alloc = [&](size_t bytes) { size_t o = off; off += (bytes + 255) & ~(size_t)255; return o; };
    bf16_t* Xb   = (bf16_t*)(ws + alloc(8192u * 1024u * 2u));       // 16 MB
    bf16_t* Wqkv = (bf16_t*)(ws + alloc(3072u * 1024u * 2u));       // 6 MB
    bf16_t* Wob  = (bf16_t*)(ws + alloc(1024u * 1024u * 2u));       // 2 MB
    float*  bqkv = (float*) (ws + alloc(3072u * 4u));
    float2* tab  = (float2*)(ws + alloc(2048u * 512u * 8u));        // 8 MB
    bf16_t* Vtmp = (bf16_t*)(ws + alloc(8192u * 1024u * 2u));       // 16 MB
    bf16_t* Qb   = (bf16_t*)(ws + alloc(64u * 2048u * 64u * 2u));   // 16 MB
    bf16_t* Kb   = (bf16_t*)(ws + alloc(64u * 2048u * 64u * 2u));   // 16 MB
    bf16_t* Vt   = (bf16_t*)(ws + alloc(64u * 64u * 2048u * 2u));   // 16 MB
    bf16_t* Ob   = Xb;  // alias: Xb is dead after GEMM1

    cvt_kernel<<<8192, 256, 0, stream>>>(queries, Xb, 2097152);
    cvt_weights<<<4096, 256, 0, stream>>>(Wq, Wk, Wv, Wo, Wqkv, Wob);
    pack_bias<<<12, 256, 0, stream>>>(bq, bk, bv, bqkv);
    rope_tab<<<4096, 256, 0, stream>>>(tab);

    gemm_qkv_rope<<<dim3(64, 24), 256, 0, stream>>>(Xb, Wqkv, bqkv, tab, Qb, Kb, Vtmp);
    repack_v<<<dim3(32, 64), 256, 0, stream>>>(Vtmp, Vt);
    attn_kernel<<<dim3(16, 64), 256, 0, stream>>>(Qb, Kb, Vt, Ob);
    gemm_bt<0><<<dim3(64, 8), 256, 0, stream>>>(Ob, Wob, bo, d_out, 8192, 1024, 1024);
}

// Round 6
// 310.831 us; speedup vs baseline: 1.0573x; 1.0573x over previous
//
#include <hip/hip_runtime.h>
#include <stdint.h>

typedef __bf16 bf16_t;
typedef __bf16 bf16x4 __attribute__((ext_vector_type(4)));
typedef __bf16 bf16x8 __attribute__((ext_vector_type(8)));
typedef float  f32x4  __attribute__((ext_vector_type(4)));

#define BB   4
#define SS   2048
#define DD   1024
#define HH   16
#define DH   64

#if __has_builtin(__builtin_amdgcn_exp2f)
#define EXP2F(x) __builtin_amdgcn_exp2f(x)
#else
#define EXP2F(x) __expf((x) * 0.6931471805599453f)
#endif

// ---------------------------------------------------------------- helpers
__device__ __forceinline__ void gload_lds16(const void* g, void* l) {
    // dest LDS addr = wave-uniform base + lane*16 (measured m104/m108)
    __builtin_amdgcn_global_load_lds(
        (__attribute__((address_space(1))) void*)(uintptr_t)g,
        (__attribute__((address_space(3))) void*)(uint32_t)(uintptr_t)l,
        16, 0, 0);
}

// ---------------------------------------------------------------- fp32 -> bf16 converts
__global__ __launch_bounds__(256) void cvt_kernel(const float* __restrict__ src,
                                                  bf16_t* __restrict__ dst, int n4) {
    int i = blockIdx.x * 256 + threadIdx.x;
    if (i < n4) {
        float4 v = ((const float4*)src)[i];
        bf16x4 o;
        o.x = (bf16_t)v.x; o.y = (bf16_t)v.y; o.z = (bf16_t)v.z; o.w = (bf16_t)v.w;
        ((bf16x4*)dst)[i] = o;
    }
}

// all four weight matrices in one launch (each 1024x1024 fp32 = 262144 float4)
__global__ __launch_bounds__(256) void cvt_weights(const float* __restrict__ Wq,
                                                   const float* __restrict__ Wk,
                                                   const float* __restrict__ Wv,
                                                   const float* __restrict__ Wo,
                                                   bf16_t* __restrict__ Wqkv,
                                                   bf16_t* __restrict__ Wob) {
    int i = blockIdx.x * 256 + threadIdx.x;      // 0 .. 4*262144
    int which = i >> 18, p = i & 262143;
    const float* src = (which == 0) ? Wq : (which == 1) ? Wk : (which == 2) ? Wv : Wo;
    bf16_t* dst = (which < 3) ? (Wqkv + (long)which * 1048576) : Wob;
    float4 v = ((const float4*)src)[p];
    bf16x4 o;
    o.x = (bf16_t)v.x; o.y = (bf16_t)v.y; o.z = (bf16_t)v.z; o.w = (bf16_t)v.w;
    ((bf16x4*)dst)[p] = o;
}

__global__ __launch_bounds__(256) void pack_bias(const float* __restrict__ bq,
                                                 const float* __restrict__ bk,
                                                 const float* __restrict__ bv,
                                                 float* __restrict__ bqkv) {
    int i = blockIdx.x * 256 + threadIdx.x;
    if (i < 3072)
        bqkv[i] = (i < 1024) ? bq[i] : ((i < 2048) ? bk[i - 1024] : bv[i - 2048]);
}

// cos/sin table: tab[s*512 + pr] = {cos(s*invf), sin(s*invf)}, invf = 10000^(-2pr/1024)
__global__ __launch_bounds__(256) void rope_tab(float2* __restrict__ tab) {
    int i = blockIdx.x * 256 + threadIdx.x;      // 2048*512
    int s = i >> 9, pr = i & 511;
    float inv = powf(10000.0f, -(float)(2 * pr) * (1.0f / 1024.0f));
    float c, sn;
    sincosf((float)s * inv, &sn, &c);
    tab[i] = make_float2(c, sn);
}

// ---------------------------------------------------------------- fused QKV GEMM + bias + RoPE
__global__ __launch_bounds__(256, 2) void gemm_qkv_rope(
        const bf16_t* __restrict__ A, const bf16_t* __restrict__ Bm,
        const float* __restrict__ bias, const float2* __restrict__ tab,
        bf16_t* __restrict__ Qb, bf16_t* __restrict__ Kb, bf16_t* __restrict__ Vtmp)
{
    __shared__ __attribute__((aligned(16))) bf16_t As[128 * 32];
    __shared__ __attribute__((aligned(16))) bf16_t Bs[128 * 32];
    const int t = threadIdx.x;
    const int lane = t & 63, w = t >> 6;
    const int wm = w >> 1, wn = w & 1;
    const int l15 = lane & 15, l4 = lane >> 4;
    const long rowA0 = (long)blockIdx.x * 128;
    const long rowB0 = (long)blockIdx.y * 128;
    const int K = 1024, N = 1024;  // per-part N

    const f32x4 vz = {0.f, 0.f, 0.f, 0.f};
    f32x4 acc[4][4];
#pragma unroll
    for (int i = 0; i < 4; ++i)
#pragma unroll
        for (int j = 0; j < 4; ++j) acc[i][j] = vz;

    for (int kk = 0; kk < K; kk += 32) {
        __syncthreads();
#pragma unroll
        for (int i = 0; i < 2; ++i) {
            const int cb = i * 256 + w * 64;
            const int c  = cb + lane;
            const int r  = c >> 2;
            const int ko = (c & 3) << 3;
            gload_lds16(A  + (rowA0 + r) * K + kk + ko, As + cb * 8);
            gload_lds16(Bm + (rowB0 + r) * K + kk + ko, Bs + cb * 8);
        }
        __syncthreads();
        bf16x8 af[4], bfr[4];
#pragma unroll
        for (int i = 0; i < 4; ++i)
            af[i] = *(const bf16x8*)(As + (wm * 64 + i * 16 + l15) * 32 + l4 * 8);
#pragma unroll
        for (int j = 0; j < 4; ++j)
            bfr[j] = *(const bf16x8*)(Bs + (wn * 64 + j * 16 + l15) * 32 + l4 * 8);
#pragma unroll
        for (int i = 0; i < 4; ++i)
#pragma unroll
            for (int j = 0; j < 4; ++j)
                acc[i][j] = __builtin_amdgcn_mfma_f32_16x16x32_bf16(af[i], bfr[j], acc[i][j], 0, 0, 0);
    }

    const long crow0 = rowA0 + wm * 64;
    const int  ccol0 = (int)rowB0 + wn * 64;     // global col in [0,3072), multiple of 64
    const int  part  = blockIdx.y >> 3;          // 0=Q, 1=K, 2=V

    if (part == 2) {
#pragma unroll
        for (int i = 0; i < 4; ++i) {
#pragma unroll
            for (int j = 0; j < 4; ++j) {
                const int col = ccol0 + j * 16 + l15;
                const float bb = bias[col];
                const int vc = col - 2048;
#pragma unroll
                for (int r = 0; r < 4; ++r) {
                    const long row = crow0 + i * 16 + l4 * 4 + r;
                    Vtmp[row * N + vc] = (bf16_t)(acc[i][j][r] + bb);
                }
            }
        }
    } else {
        bf16_t* dst0 = part ? Kb : Qb;
        const int h = (ccol0 & 1023) >> 6;       // this wave's 64-col strip = one head
#pragma unroll
        for (int i = 0; i < 4; ++i) {
#pragma unroll
            for (int j = 0; j < 4; ++j) {
                const int col = ccol0 + j * 16 + l15;
                const float bb = bias[col];
                const int even = !(col & 1);
                const int dd = j * 16 + l15;
                const float2* trow = tab + (col >> 1 & 511);
#pragma unroll
                for (int r = 0; r < 4; ++r) {
                    const long row = crow0 + i * 16 + l4 * 4 + r;
                    const int b = (int)(row >> 11), s = (int)(row & 2047);
                    const float val = acc[i][j][r] + bb;
                    const float par = __shfl_xor(val, 1);
                    const float2 cs = trow[s * 512];
                    const float out = even ? (val * cs.x - par * cs.y)
                                           : fmaf(val, cs.x, par * cs.y);
                    dst0[((long)((b * HH + h) * SS + s)) * DH + dd] = (bf16_t)out;
                }
            }
        }
    }
}

// ---------------------------------------------------------------- NT GEMM (output projection)
template <int OUT_BF16>
__global__ __launch_bounds__(256, 2) void gemm_bt(
        const bf16_t* __restrict__ A, const bf16_t* __restrict__ Bm,
        const float* __restrict__ bias, void* __restrict__ Cout,
        int M, int N, int K)
{
    __shared__ __attribute__((aligned(16))) bf16_t As[128 * 32];
    __shared__ __attribute__((aligned(16))) bf16_t Bs[128 * 32];
    const int t = threadIdx.x;
    const int lane = t & 63, w = t >> 6;
    const int wm = w >> 1, wn = w & 1;
    const int l15 = lane & 15, l4 = lane >> 4;
    const long rowA0 = (long)blockIdx.x * 128;
    const long rowB0 = (long)blockIdx.y * 128;

    const f32x4 vz = {0.f, 0.f, 0.f, 0.f};
    f32x4 acc[4][4];
#pragma unroll
    for (int i = 0; i < 4; ++i)
#pragma unroll
        for (int j = 0; j < 4; ++j) acc[i][j] = vz;

    for (int kk = 0; kk < K; kk += 32) {
        __syncthreads();
#pragma unroll
        for (int i = 0; i < 2; ++i) {
            const int cb = i * 256 + w * 64;
            const int c  = cb + lane;
            const int r  = c >> 2;
            const int ko = (c & 3) << 3;
            gload_lds16(A  + (rowA0 + r) * K + kk + ko, As + cb * 8);
            gload_lds16(Bm + (rowB0 + r) * K + kk + ko, Bs + cb * 8);
        }
        __syncthreads();
        bf16x8 af[4], bfr[4];
#pragma unroll
        for (int i = 0; i < 4; ++i)
            af[i] = *(const bf16x8*)(As + (wm * 64 + i * 16 + l15) * 32 + l4 * 8);
#pragma unroll
        for (int j = 0; j < 4; ++j)
            bfr[j] = *(const bf16x8*)(Bs + (wn * 64 + j * 16 + l15) * 32 + l4 * 8);
#pragma unroll
        for (int i = 0; i < 4; ++i)
#pragma unroll
            for (int j = 0; j < 4; ++j)
                acc[i][j] = __builtin_amdgcn_mfma_f32_16x16x32_bf16(af[i], bfr[j], acc[i][j], 0, 0, 0);
    }

    const long crow0 = rowA0 + wm * 64;
    const int  ccol0 = (int)rowB0 + wn * 64;
#pragma unroll
    for (int i = 0; i < 4; ++i) {
#pragma unroll
        for (int j = 0; j < 4; ++j) {
            const int col = ccol0 + j * 16 + l15;
            const float bb = bias[col];
#pragma unroll
            for (int r = 0; r < 4; ++r) {
                const long row = crow0 + i * 16 + l4 * 4 + r;
                const float v = acc[i][j][r] + bb;
                if (OUT_BF16) ((bf16_t*)Cout)[row * N + col] = (bf16_t)v;
                else          ((float*)Cout)[row * N + col]  = v;
            }
        }
    }
}

// ---------------------------------------------------------------- V transpose repack
// Vtmp (n, h*64+d) -> Vt (b*H+h, dh, s) bf16
__global__ __launch_bounds__(256) void repack_v(const bf16_t* __restrict__ Vtmp,
                                                bf16_t* __restrict__ Vt)
{
    __shared__ bf16_t tile[64][65];
    const int t = threadIdx.x;
    const int st = blockIdx.x, bh = blockIdx.y;
    const int b = bh >> 4, h = bh & 15;
    const long nbase = (long)b * SS + st * 64;
#pragma unroll
    for (int e = 0; e < 16; ++e) {
        const int i = e * 256 + t;
        const int r = i >> 6, d = i & 63;
        tile[r][d] = Vtmp[(nbase + r) * 1024 + h * 64 + d];
    }
    __syncthreads();
#pragma unroll
    for (int e = 0; e < 16; ++e) {
        const int i = e * 256 + t;
        const int d = i >> 6, s = i & 63;
        Vt[((long)bh * DH + d) * SS + st * 64 + s] = tile[s][d];
    }
}

// ---------------------------------------------------------------- flash attention
// grid (16 q-tiles of 128, 64 bh). 4 waves; wave w owns q rows
// [qt*128 + w*32, +32) as TWO 16-row strips (s = 0,1).
//
// R6 = R3's proven structure (117 us, conflict-clean) + 2x q per wave:
// every kf/vf fragment read from LDS now feeds BOTH strips' MFMAs, cutting
// LDS bytes per q-row ~40%. All LDS access patterns are byte-identical to
// R3's measured-clean ones (Ks/Vs octet XOR swizzle, Ps pitch 72, b64 P
// writes, wave-local P round-trip with no barrier). R4/R5 lessons: pitch-64
// octet swizzle breaks when a wave spans 32 rows (4-way), and shfl_xor(32)
// B-frag assembly costs more VALU+ds_permute than the wave-local LDS
// round-trip it replaces — don't go back there.
// __launch_bounds__(256,4): cap VGPR at 128 so occupancy stays at the LDS
// limit (34.8 KB -> 4 blocks/CU).
__global__ __launch_bounds__(256, 4) void attn_kernel(const bf16_t* __restrict__ Qb,
                                                      const bf16_t* __restrict__ Kb,
                                                      const bf16_t* __restrict__ Vt,
                                                      bf16_t* __restrict__ Ob)
{
    __shared__ __attribute__((aligned(16))) bf16_t Ks[64 * 64];   // [key][d], swizzled
    __shared__ __attribute__((aligned(16))) bf16_t Vs[64 * 64];   // [d][key], swizzled
    __shared__ __attribute__((aligned(16))) bf16_t Ps[128 * 72];  // [q][key], pitch 72
    const int t = threadIdx.x, lane = t & 63, w = t >> 6;
    const int l15 = lane & 15, l4 = lane >> 4;
    const int xr = l15 & 7;               // read-side swizzle pattern (= row&7)
    const int qt = blockIdx.x, bh = blockIdx.y;
    const bf16_t* Qbh = Qb + (long)bh * SS * DH;
    const bf16_t* Kbh = Kb + (long)bh * SS * DH;
    const bf16_t* Vbh = Vt + (long)bh * DH * SS;

    const int qbase = qt * 128 + w * 32;
    bf16x8 qf[2][2];
#pragma unroll
    for (int s = 0; s < 2; ++s) {
        const long qrow = qbase + 16 * s + l15;
        qf[s][0] = *(const bf16x8*)(Qbh + qrow * DH + l4 * 8);
        qf[s][1] = *(const bf16x8*)(Qbh + qrow * DH + 32 + l4 * 8);
    }

    const f32x4 vz = {0.f, 0.f, 0.f, 0.f};
    f32x4 oacc[2][4];
#pragma unroll
    for (int s = 0; s < 2; ++s)
#pragma unroll
        for (int j = 0; j < 4; ++j) oacc[s][j] = vz;
    float l_sum[2] = {0.f, 0.f};

    int srow[2], scc[2];
#pragma unroll
    for (int i = 0; i < 2; ++i) {
        const int L = i * 256 + w * 64 + lane;
        srow[i] = L >> 3;
        scc[i]  = (L & 7) ^ (srow[i] & 7);
    }

    const float SC = 0.125f * 1.4426950408889634f;
    const float BI = -8.0f  * 1.4426950408889634f;

    for (int kt = 0; kt < SS / 64; ++kt) {
        __syncthreads();
        const bf16_t* Ksrc = Kbh + (long)kt * 64 * DH;
#pragma unroll
        for (int i = 0; i < 2; ++i) {
            const int cb = i * 256 + w * 64;
            gload_lds16(Ksrc + srow[i] * 64 + scc[i] * 8, Ks + cb * 8);
            gload_lds16(Vbh + (long)srow[i] * SS + kt * 64 + scc[i] * 8, Vs + cb * 8);
        }
        __syncthreads();

        // S^T = K Q^T for both strips; kf shared across strips
        f32x4 sacc[2][4];
#pragma unroll
        for (int s = 0; s < 2; ++s)
#pragma unroll
            for (int j = 0; j < 4; ++j) sacc[s][j] = vz;
#pragma unroll
        for (int j = 0; j < 4; ++j) {
            const int rk = (j * 16 + l15) * 64;
            const bf16x8 kf0 = *(const bf16x8*)(Ks + rk + ((l4 ^ xr) * 8));
            const bf16x8 kf1 = *(const bf16x8*)(Ks + rk + (((4 + l4) ^ xr) * 8));
#pragma unroll
            for (int s = 0; s < 2; ++s) {
                sacc[s][j] = __builtin_amdgcn_mfma_f32_16x16x32_bf16(kf0, qf[s][0], sacc[s][j], 0, 0, 0);
                sacc[s][j] = __builtin_amdgcn_mfma_f32_16x16x32_bf16(kf1, qf[s][1], sacc[s][j], 0, 0, 0);
            }
        }

        // p = exp2(s*SC + BI); lane holds q' = l15 (col), keys j*16 + l4*4 + r
#pragma unroll
        for (int s = 0; s < 2; ++s) {
#pragma unroll
            for (int j = 0; j < 4; ++j) {
                const float p0 = EXP2F(fmaf(sacc[s][j][0], SC, BI));
                const float p1 = EXP2F(fmaf(sacc[s][j][1], SC, BI));
                const float p2 = EXP2F(fmaf(sacc[s][j][2], SC, BI));
                const float p3 = EXP2F(fmaf(sacc[s][j][3], SC, BI));
                l_sum[s] += (p0 + p1) + (p2 + p3);
                bf16x4 pk;
                pk.x = (bf16_t)p0; pk.y = (bf16_t)p1; pk.z = (bf16_t)p2; pk.w = (bf16_t)p3;
                *(bf16x4*)(Ps + (w * 32 + 16 * s + l15) * 72 + j * 16 + l4 * 4) = pk;
            }
        }
        // no __syncthreads(): Ps rows [w*32, w*32+32) are wave-local;
        // in-wave DS ops complete in order.

        bf16x8 pf[2][2];
#pragma unroll
        for (int s = 0; s < 2; ++s) {
            pf[s][0] = *(const bf16x8*)(Ps + (w * 32 + 16 * s + l15) * 72 + l4 * 8);
            pf[s][1] = *(const bf16x8*)(Ps + (w * 32 + 16 * s + l15) * 72 + 32 + l4 * 8);
        }
#pragma unroll
        for (int j = 0; j < 4; ++j) {
            const int rv = (j * 16 + l15) * 64;
            const bf16x8 vf0 = *(const bf16x8*)(Vs + rv + ((l4 ^ xr) * 8));
            const bf16x8 vf1 = *(const bf16x8*)(Vs + rv + (((4 + l4) ^ xr) * 8));
#pragma unroll
            for (int s = 0; s < 2; ++s) {
                oacc[s][j] = __builtin_amdgcn_mfma_f32_16x16x32_bf16(pf[s][0], vf0, oacc[s][j], 0, 0, 0);
                oacc[s][j] = __builtin_amdgcn_mfma_f32_16x16x32_bf16(pf[s][1], vf1, oacc[s][j], 0, 0, 0);
            }
        }
    }

    const int b = bh >> 4, h = bh & 15;
#pragma unroll
    for (int s = 0; s < 2; ++s) {
        float lt = l_sum[s];
        lt += __shfl_xor(lt, 16);
        lt += __shfl_xor(lt, 32);
        const float inv = 1.0f / lt;
        float invr[4];
#pragma unroll
        for (int r = 0; r < 4; ++r)
            invr[r] = __shfl(inv, l4 * 4 + r);   // lane l4*4+r holds inv for q'=l4*4+r
#pragma unroll
        for (int j = 0; j < 4; ++j) {
#pragma unroll
            for (int r = 0; r < 4; ++r) {
                const int row = qbase + 16 * s + l4 * 4 + r;
                const float v = oacc[s][j][r] * invr[r];
                Ob[((long)(b * SS + row)) * DD + h * DH + j * 16 + l15] = (bf16_t)v;
            }
        }
    }
}

// ---------------------------------------------------------------- launch
extern "C" void kernel_launch(void* const* d_in, const int* in_sizes, int n_in,
                              void* d_out, int out_size, void* d_ws, size_t ws_size,
                              hipStream_t stream)
{
    const float* queries = (const float*)d_in[0];
    const float* Wq = (const float*)d_in[1];
    const float* bq = (const float*)d_in[2];
    const float* Wk = (const float*)d_in[3];
    const float* bk = (const float*)d_in[4];
    const float* Wv = (const float*)d_in[5];
    const float* bv = (const float*)d_in[6];
    const float* Wo = (const float*)d_in[7];
    const float* bo = (const float*)d_in[8];

    char* ws = (char*)d_ws;
    size_t off = 0;
    auto alloc = [&](size_t bytes) { size_t o = off; off += (bytes + 255) & ~(size_t)255; return o; };
    bf16_t* Xb   = (bf16_t*)(ws + alloc(8192u * 1024u * 2u));       // 16 MB
    bf16_t* Wqkv = (bf16_t*)(ws + alloc(3072u * 1024u * 2u));       // 6 MB
    bf16_t* Wob  = (bf16_t*)(ws + alloc(1024u * 1024u * 2u));       // 2 MB
    float*  bqkv = (float*) (ws + alloc(3072u * 4u));
    float2* tab  = (float2*)(ws + alloc(2048u * 512u * 8u));        // 8 MB
    bf16_t* Vtmp = (bf16_t*)(ws + alloc(8192u * 1024u * 2u));       // 16 MB
    bf16_t* Qb   = (bf16_t*)(ws + alloc(64u * 2048u * 64u * 2u));   // 16 MB
    bf16_t* Kb   = (bf16_t*)(ws + alloc(64u * 2048u * 64u * 2u));   // 16 MB
    bf16_t* Vt   = (bf16_t*)(ws + alloc(64u * 64u * 2048u * 2u));   // 16 MB
    bf16_t* Ob   = Xb;  // alias: Xb is dead after GEMM1

    cvt_kernel<<<8192, 256, 0, stream>>>(queries, Xb, 2097152);
    cvt_weights<<<4096, 256, 0, stream>>>(Wq, Wk, Wv, Wo, Wqkv, Wob);
    pack_bias<<<12, 256, 0, stream>>>(bq, bk, bv, bqkv);
    rope_tab<<<4096, 256, 0, stream>>>(tab);

    gemm_qkv_rope<<<dim3(64, 24), 256, 0, stream>>>(Xb, Wqkv, bqkv, tab, Qb, Kb, Vtmp);
    repack_v<<<dim3(32, 64), 256, 0, stream>>>(Vtmp, Vt);
    attn_kernel<<<dim3(16, 64), 256, 0, stream>>>(Qb, Kb, Vt, Ob);
    gemm_bt<0><<<dim3(64, 8), 256, 0, stream>>>(Ob, Wob, bo, d_out, 8192, 1024, 1024);
}

// Round 7
// 301.495 us; speedup vs baseline: 1.0900x; 1.0310x over previous
//
#include <hip/hip_runtime.h>
#include <stdint.h>

typedef __bf16 bf16_t;
typedef __bf16 bf16x4 __attribute__((ext_vector_type(4)));
typedef __bf16 bf16x8 __attribute__((ext_vector_type(8)));
typedef float  f32x4  __attribute__((ext_vector_type(4)));

#define BB   4
#define SS   2048
#define DD   1024
#define HH   16
#define DH   64

#if __has_builtin(__builtin_amdgcn_exp2f)
#define EXP2F(x) __builtin_amdgcn_exp2f(x)
#else
#define EXP2F(x) __expf((x) * 0.6931471805599453f)
#endif

// ---------------------------------------------------------------- helpers
__device__ __forceinline__ void gload_lds16(const void* g, void* l) {
    // dest LDS addr = wave-uniform base + lane*16 (measured m104/m108)
    __builtin_amdgcn_global_load_lds(
        (__attribute__((address_space(1))) void*)(uintptr_t)g,
        (__attribute__((address_space(3))) void*)(uint32_t)(uintptr_t)l,
        16, 0, 0);
}

// ---------------------------------------------------------------- fused prep
// one launch: X fp32->bf16 (8192 blocks), 4 weights fp32->bf16 (4096),
// rope cos/sin table (4096), bias pack (12). grid = 16396.
__global__ __launch_bounds__(256) void prep_kernel(
        const float* __restrict__ queries,
        const float* __restrict__ Wq, const float* __restrict__ Wk,
        const float* __restrict__ Wv, const float* __restrict__ Wo,
        const float* __restrict__ bq, const float* __restrict__ bk,
        const float* __restrict__ bv,
        bf16_t* __restrict__ Xb, bf16_t* __restrict__ Wqkv,
        bf16_t* __restrict__ Wob, float* __restrict__ bqkv,
        float2* __restrict__ tab)
{
    const int bid = blockIdx.x, t = threadIdx.x;
    if (bid < 8192) {                       // X convert: 2097152 float4
        const int i = bid * 256 + t;
        float4 v = ((const float4*)queries)[i];
        bf16x4 o;
        o.x = (bf16_t)v.x; o.y = (bf16_t)v.y; o.z = (bf16_t)v.z; o.w = (bf16_t)v.w;
        ((bf16x4*)Xb)[i] = o;
    } else if (bid < 12288) {               // weights: 1048576 float4
        const int i = (bid - 8192) * 256 + t;
        const int which = i >> 18, p = i & 262143;
        const float* src = (which == 0) ? Wq : (which == 1) ? Wk : (which == 2) ? Wv : Wo;
        bf16_t* dst = (which < 3) ? (Wqkv + (long)which * 1048576) : Wob;
        float4 v = ((const float4*)src)[p];
        bf16x4 o;
        o.x = (bf16_t)v.x; o.y = (bf16_t)v.y; o.z = (bf16_t)v.z; o.w = (bf16_t)v.w;
        ((bf16x4*)dst)[p] = o;
    } else if (bid < 16384) {               // rope table: 2048*512 entries
        const int i = (bid - 12288) * 256 + t;
        const int s = i >> 9, pr = i & 511;
        float inv = powf(10000.0f, -(float)(2 * pr) * (1.0f / 1024.0f));
        float c, sn;
        sincosf((float)s * inv, &sn, &c);
        tab[i] = make_float2(c, sn);
    } else {                                // bias pack: 3072
        const int i = (bid - 16384) * 256 + t;
        if (i < 3072)
            bqkv[i] = (i < 1024) ? bq[i] : ((i < 2048) ? bk[i - 1024] : bv[i - 2048]);
    }
}

// ---------------------------------------------------------------- fused QKV GEMM + bias + RoPE
__global__ __launch_bounds__(256, 2) void gemm_qkv_rope(
        const bf16_t* __restrict__ A, const bf16_t* __restrict__ Bm,
        const float* __restrict__ bias, const float2* __restrict__ tab,
        bf16_t* __restrict__ Qb, bf16_t* __restrict__ Kb, bf16_t* __restrict__ Vtmp)
{
    __shared__ __attribute__((aligned(16))) bf16_t As[128 * 32];
    __shared__ __attribute__((aligned(16))) bf16_t Bs[128 * 32];
    const int t = threadIdx.x;
    const int lane = t & 63, w = t >> 6;
    const int wm = w >> 1, wn = w & 1;
    const int l15 = lane & 15, l4 = lane >> 4;
    const long rowA0 = (long)blockIdx.x * 128;
    const long rowB0 = (long)blockIdx.y * 128;
    const int K = 1024, N = 1024;  // per-part N

    const f32x4 vz = {0.f, 0.f, 0.f, 0.f};
    f32x4 acc[4][4];
#pragma unroll
    for (int i = 0; i < 4; ++i)
#pragma unroll
        for (int j = 0; j < 4; ++j) acc[i][j] = vz;

    for (int kk = 0; kk < K; kk += 32) {
        __syncthreads();
#pragma unroll
        for (int i = 0; i < 2; ++i) {
            const int cb = i * 256 + w * 64;
            const int c  = cb + lane;
            const int r  = c >> 2;
            const int ko = (c & 3) << 3;
            gload_lds16(A  + (rowA0 + r) * K + kk + ko, As + cb * 8);
            gload_lds16(Bm + (rowB0 + r) * K + kk + ko, Bs + cb * 8);
        }
        __syncthreads();
        bf16x8 af[4], bfr[4];
#pragma unroll
        for (int i = 0; i < 4; ++i)
            af[i] = *(const bf16x8*)(As + (wm * 64 + i * 16 + l15) * 32 + l4 * 8);
#pragma unroll
        for (int j = 0; j < 4; ++j)
            bfr[j] = *(const bf16x8*)(Bs + (wn * 64 + j * 16 + l15) * 32 + l4 * 8);
#pragma unroll
        for (int i = 0; i < 4; ++i)
#pragma unroll
            for (int j = 0; j < 4; ++j)
                acc[i][j] = __builtin_amdgcn_mfma_f32_16x16x32_bf16(af[i], bfr[j], acc[i][j], 0, 0, 0);
    }

    const long crow0 = rowA0 + wm * 64;
    const int  ccol0 = (int)rowB0 + wn * 64;     // global col in [0,3072), multiple of 64
    const int  part  = blockIdx.y >> 3;          // 0=Q, 1=K, 2=V

    if (part == 2) {
#pragma unroll
        for (int i = 0; i < 4; ++i) {
#pragma unroll
            for (int j = 0; j < 4; ++j) {
                const int col = ccol0 + j * 16 + l15;
                const float bb = bias[col];
                const int vc = col - 2048;
#pragma unroll
                for (int r = 0; r < 4; ++r) {
                    const long row = crow0 + i * 16 + l4 * 4 + r;
                    Vtmp[row * N + vc] = (bf16_t)(acc[i][j][r] + bb);
                }
            }
        }
    } else {
        bf16_t* dst0 = part ? Kb : Qb;
        const int h = (ccol0 & 1023) >> 6;       // this wave's 64-col strip = one head
#pragma unroll
        for (int i = 0; i < 4; ++i) {
#pragma unroll
            for (int j = 0; j < 4; ++j) {
                const int col = ccol0 + j * 16 + l15;
                const float bb = bias[col];
                const int even = !(col & 1);
                const int dd = j * 16 + l15;
                const float2* trow = tab + (col >> 1 & 511);
#pragma unroll
                for (int r = 0; r < 4; ++r) {
                    const long row = crow0 + i * 16 + l4 * 4 + r;
                    const int b = (int)(row >> 11), s = (int)(row & 2047);
                    const float val = acc[i][j][r] + bb;
                    const float par = __shfl_xor(val, 1);
                    const float2 cs = trow[s * 512];
                    const float out = even ? (val * cs.x - par * cs.y)
                                           : fmaf(val, cs.x, par * cs.y);
                    dst0[((long)((b * HH + h) * SS + s)) * DH + dd] = (bf16_t)out;
                }
            }
        }
    }
}

// ---------------------------------------------------------------- NT GEMM (output projection)
template <int OUT_BF16>
__global__ __launch_bounds__(256, 2) void gemm_bt(
        const bf16_t* __restrict__ A, const bf16_t* __restrict__ Bm,
        const float* __restrict__ bias, void* __restrict__ Cout,
        int M, int N, int K)
{
    __shared__ __attribute__((aligned(16))) bf16_t As[128 * 32];
    __shared__ __attribute__((aligned(16))) bf16_t Bs[128 * 32];
    const int t = threadIdx.x;
    const int lane = t & 63, w = t >> 6;
    const int wm = w >> 1, wn = w & 1;
    const int l15 = lane & 15, l4 = lane >> 4;
    const long rowA0 = (long)blockIdx.x * 128;
    const long rowB0 = (long)blockIdx.y * 128;

    const f32x4 vz = {0.f, 0.f, 0.f, 0.f};
    f32x4 acc[4][4];
#pragma unroll
    for (int i = 0; i < 4; ++i)
#pragma unroll
        for (int j = 0; j < 4; ++j) acc[i][j] = vz;

    for (int kk = 0; kk < K; kk += 32) {
        __syncthreads();
#pragma unroll
        for (int i = 0; i < 2; ++i) {
            const int cb = i * 256 + w * 64;
            const int c  = cb + lane;
            const int r  = c >> 2;
            const int ko = (c & 3) << 3;
            gload_lds16(A  + (rowA0 + r) * K + kk + ko, As + cb * 8);
            gload_lds16(Bm + (rowB0 + r) * K + kk + ko, Bs + cb * 8);
        }
        __syncthreads();
        bf16x8 af[4], bfr[4];
#pragma unroll
        for (int i = 0; i < 4; ++i)
            af[i] = *(const bf16x8*)(As + (wm * 64 + i * 16 + l15) * 32 + l4 * 8);
#pragma unroll
        for (int j = 0; j < 4; ++j)
            bfr[j] = *(const bf16x8*)(Bs + (wn * 64 + j * 16 + l15) * 32 + l4 * 8);
#pragma unroll
        for (int i = 0; i < 4; ++i)
#pragma unroll
            for (int j = 0; j < 4; ++j)
                acc[i][j] = __builtin_amdgcn_mfma_f32_16x16x32_bf16(af[i], bfr[j], acc[i][j], 0, 0, 0);
    }

    const long crow0 = rowA0 + wm * 64;
    const int  ccol0 = (int)rowB0 + wn * 64;
#pragma unroll
    for (int i = 0; i < 4; ++i) {
#pragma unroll
        for (int j = 0; j < 4; ++j) {
            const int col = ccol0 + j * 16 + l15;
            const float bb = bias[col];
#pragma unroll
            for (int r = 0; r < 4; ++r) {
                const long row = crow0 + i * 16 + l4 * 4 + r;
                const float v = acc[i][j][r] + bb;
                if (OUT_BF16) ((bf16_t*)Cout)[row * N + col] = (bf16_t)v;
                else          ((float*)Cout)[row * N + col]  = v;
            }
        }
    }
}

// ---------------------------------------------------------------- V transpose repack
// Vtmp (n, h*64+d) -> Vt (b*H+h, dh, s) bf16.  Vectorized: 2x b128 gload +
// LDS tile (pitch 66: load-phase b32 writes octet-distinct; read-phase scalar
// reads 2-way max = free; 66*2 B rows keep b128 8B... reads are scalar) +
// 2x b128 gstore (128 B contiguous per octet).
__global__ __launch_bounds__(256) void repack_v(const bf16_t* __restrict__ Vtmp,
                                                bf16_t* __restrict__ Vt)
{
    __shared__ bf16_t tile[64][66];
    const int t = threadIdx.x;
    const int st = blockIdx.x, bh = blockIdx.y;
    const int b = bh >> 4, h = bh & 15;
    const long nbase = (long)b * SS + st * 64;
    const int rr = t >> 3, c8 = (t & 7) * 8;
#pragma unroll
    for (int e = 0; e < 2; ++e) {
        const int r = e * 32 + rr;
        union { bf16x8 v; unsigned int u[4]; } ld;
        ld.v = *(const bf16x8*)(Vtmp + (nbase + r) * 1024 + h * 64 + c8);
#pragma unroll
        for (int k = 0; k < 4; ++k)
            *(unsigned int*)(&tile[r][c8 + 2 * k]) = ld.u[k];
    }
    __syncthreads();
#pragma unroll
    for (int e = 0; e < 2; ++e) {
        const int d = e * 32 + rr;
        bf16x8 o;
#pragma unroll
        for (int k = 0; k < 8; ++k) o[k] = tile[c8 + k][d];
        *(bf16x8*)(Vt + ((long)bh * DH + d) * SS + st * 64 + c8) = o;
    }
}

// ---------------------------------------------------------------- flash attention
// grid (16 q-tiles of 128, 64 bh). 4 waves; wave w owns q rows
// [qt*128 + w*32, +32) as TWO 16-row strips (s = 0,1).
//
// R7 = R6 (95.5 us, conflict-clean) + double-buffered K/V staging with ONE
// barrier per iter: stage(kt+1 -> buf^1); compute(buf); __syncthreads().
// The compiler's forced vmcnt(0) before s_barrier now lands after the full
// compute phase, hiding the DMA instead of exposing it between R6's two
// barriers. LDS 51.2 KB -> 3 blocks/CU (was 4 at measured 33.7% occupancy,
// so the cap barely binds). R4/R5 lessons still apply: pitch-64 octet
// swizzle breaks for 32-row spans; shfl-based B-frag assembly costs more
// than the wave-local Ps round-trip.
__global__ __launch_bounds__(256, 3) void attn_kernel(const bf16_t* __restrict__ Qb,
                                                      const bf16_t* __restrict__ Kb,
                                                      const bf16_t* __restrict__ Vt,
                                                      bf16_t* __restrict__ Ob)
{
    __shared__ __attribute__((aligned(16))) bf16_t Ks[2][64 * 64];  // [buf][key][d]
    __shared__ __attribute__((aligned(16))) bf16_t Vs[2][64 * 64];  // [buf][d][key]
    __shared__ __attribute__((aligned(16))) bf16_t Ps[128 * 72];    // [q][key], pitch 72
    const int t = threadIdx.x, lane = t & 63, w = t >> 6;
    const int l15 = lane & 15, l4 = lane >> 4;
    const int xr = l15 & 7;               // read-side swizzle pattern (= row&7)
    const int qt = blockIdx.x, bh = blockIdx.y;
    const bf16_t* Qbh = Qb + (long)bh * SS * DH;
    const bf16_t* Kbh = Kb + (long)bh * SS * DH;
    const bf16_t* Vbh = Vt + (long)bh * DH * SS;

    const int qbase = qt * 128 + w * 32;
    bf16x8 qf[2][2];
#pragma unroll
    for (int s = 0; s < 2; ++s) {
        const long qrow = qbase + 16 * s + l15;
        qf[s][0] = *(const bf16x8*)(Qbh + qrow * DH + l4 * 8);
        qf[s][1] = *(const bf16x8*)(Qbh + qrow * DH + 32 + l4 * 8);
    }

    const f32x4 vz = {0.f, 0.f, 0.f, 0.f};
    f32x4 oacc[2][4];
#pragma unroll
    for (int s = 0; s < 2; ++s)
#pragma unroll
        for (int j = 0; j < 4; ++j) oacc[s][j] = vz;
    float l_sum[2] = {0.f, 0.f};

    int srow[2], scc[2];
#pragma unroll
    for (int i = 0; i < 2; ++i) {
        const int L = i * 256 + w * 64 + lane;
        srow[i] = L >> 3;
        scc[i]  = (L & 7) ^ (srow[i] & 7);
    }

    const float SC = 0.125f * 1.4426950408889634f;
    const float BI = -8.0f  * 1.4426950408889634f;

    auto stage = [&](int kt, int buf) {
        const bf16_t* Ksrc = Kbh + (long)kt * 64 * DH;
#pragma unroll
        for (int i = 0; i < 2; ++i) {
            const int cb = i * 256 + w * 64;
            gload_lds16(Ksrc + srow[i] * 64 + scc[i] * 8, &Ks[buf][cb * 8]);
            gload_lds16(Vbh + (long)srow[i] * SS + kt * 64 + scc[i] * 8, &Vs[buf][cb * 8]);
        }
    };

    stage(0, 0);
    __syncthreads();                      // drains prologue DMA

    for (int kt = 0; kt < SS / 64; ++kt) {
        const int p = kt & 1;
        if (kt + 1 < SS / 64) stage(kt + 1, p ^ 1);   // overlaps with compute below
        const bf16_t* KsP = Ks[p];
        const bf16_t* VsP = Vs[p];

        // S^T = K Q^T for both strips; kf shared across strips
        f32x4 sacc[2][4];
#pragma unroll
        for (int s = 0; s < 2; ++s)
#pragma unroll
            for (int j = 0; j < 4; ++j) sacc[s][j] = vz;
#pragma unroll
        for (int j = 0; j < 4; ++j) {
            const int rk = (j * 16 + l15) * 64;
            const bf16x8 kf0 = *(const bf16x8*)(KsP + rk + ((l4 ^ xr) * 8));
            const bf16x8 kf1 = *(const bf16x8*)(KsP + rk + (((4 + l4) ^ xr) * 8));
#pragma unroll
            for (int s = 0; s < 2; ++s) {
                sacc[s][j] = __builtin_amdgcn_mfma_f32_16x16x32_bf16(kf0, qf[s][0], sacc[s][j], 0, 0, 0);
                sacc[s][j] = __builtin_amdgcn_mfma_f32_16x16x32_bf16(kf1, qf[s][1], sacc[s][j], 0, 0, 0);
            }
        }

        // p = exp2(s*SC + BI); lane holds q' = l15 (col), keys j*16 + l4*4 + r
#pragma unroll
        for (int s = 0; s < 2; ++s) {
#pragma unroll
            for (int j = 0; j < 4; ++j) {
                const float p0 = EXP2F(fmaf(sacc[s][j][0], SC, BI));
                const float p1 = EXP2F(fmaf(sacc[s][j][1], SC, BI));
                const float p2 = EXP2F(fmaf(sacc[s][j][2], SC, BI));
                const float p3 = EXP2F(fmaf(sacc[s][j][3], SC, BI));
                l_sum[s] += (p0 + p1) + (p2 + p3);
                bf16x4 pk;
                pk.x = (bf16_t)p0; pk.y = (bf16_t)p1; pk.z = (bf16_t)p2; pk.w = (bf16_t)p3;
                *(bf16x4*)(Ps + (w * 32 + 16 * s + l15) * 72 + j * 16 + l4 * 4) = pk;
            }
        }
        // no barrier: Ps rows [w*32, w*32+32) are wave-local; in-wave DS ordered

        bf16x8 pf[2][2];
#pragma unroll
        for (int s = 0; s < 2; ++s) {
            pf[s][0] = *(const bf16x8*)(Ps + (w * 32 + 16 * s + l15) * 72 + l4 * 8);
            pf[s][1] = *(const bf16x8*)(Ps + (w * 32 + 16 * s + l15) * 72 + 32 + l4 * 8);
        }
#pragma unroll
        for (int j = 0; j < 4; ++j) {
            const int rv = (j * 16 + l15) * 64;
            const bf16x8 vf0 = *(const bf16x8*)(VsP + rv + ((l4 ^ xr) * 8));
            const bf16x8 vf1 = *(const bf16x8*)(VsP + rv + (((4 + l4) ^ xr) * 8));
#pragma unroll
            for (int s = 0; s < 2; ++s) {
                oacc[s][j] = __builtin_amdgcn_mfma_f32_16x16x32_bf16(pf[s][0], vf0, oacc[s][j], 0, 0, 0);
                oacc[s][j] = __builtin_amdgcn_mfma_f32_16x16x32_bf16(pf[s][1], vf1, oacc[s][j], 0, 0, 0);
            }
        }

        __syncthreads();   // drains next-tile DMA (hidden behind compute) and
                           // guards buf[p] against overwrite at iter kt+1
    }

    const int b = bh >> 4, h = bh & 15;
#pragma unroll
    for (int s = 0; s < 2; ++s) {
        float lt = l_sum[s];
        lt += __shfl_xor(lt, 16);
        lt += __shfl_xor(lt, 32);
        const float inv = 1.0f / lt;
        float invr[4];
#pragma unroll
        for (int r = 0; r < 4; ++r)
            invr[r] = __shfl(inv, l4 * 4 + r);   // lane l4*4+r holds inv for q'=l4*4+r
#pragma unroll
        for (int j = 0; j < 4; ++j) {
#pragma unroll
            for (int r = 0; r < 4; ++r) {
                const int row = qbase + 16 * s + l4 * 4 + r;
                const float v = oacc[s][j][r] * invr[r];
                Ob[((long)(b * SS + row)) * DD + h * DH + j * 16 + l15] = (bf16_t)v;
            }
        }
    }
}

// ---------------------------------------------------------------- launch
extern "C" void kernel_launch(void* const* d_in, const int* in_sizes, int n_in,
                              void* d_out, int out_size, void* d_ws, size_t ws_size,
                              hipStream_t stream)
{
    const float* queries = (const float*)d_in[0];
    const float* Wq = (const float*)d_in[1];
    const float* bq = (const float*)d_in[2];
    const float* Wk = (const float*)d_in[3];
    const float* bk = (const float*)d_in[4];
    const float* Wv = (const float*)d_in[5];
    const float* bv = (const float*)d_in[6];
    const float* Wo = (const float*)d_in[7];
    const float* bo = (const float*)d_in[8];

    char* ws = (char*)d_ws;
    size_t off = 0;
    auto alloc = [&](size_t bytes) { size_t o = off; off += (bytes + 255) & ~(size_t)255; return o; };
    bf16_t* Xb   = (bf16_t*)(ws + alloc(8192u * 1024u * 2u));       // 16 MB
    bf16_t* Wqkv = (bf16_t*)(ws + alloc(3072u * 1024u * 2u));       // 6 MB
    bf16_t* Wob  = (bf16_t*)(ws + alloc(1024u * 1024u * 2u));       // 2 MB
    float*  bqkv = (float*) (ws + alloc(3072u * 4u));
    float2* tab  = (float2*)(ws + alloc(2048u * 512u * 8u));        // 8 MB
    bf16_t* Vtmp = (bf16_t*)(ws + alloc(8192u * 1024u * 2u));       // 16 MB
    bf16_t* Qb   = (bf16_t*)(ws + alloc(64u * 2048u * 64u * 2u));   // 16 MB
    bf16_t* Kb   = (bf16_t*)(ws + alloc(64u * 2048u * 64u * 2u));   // 16 MB
    bf16_t* Vt   = (bf16_t*)(ws + alloc(64u * 64u * 2048u * 2u));   // 16 MB
    bf16_t* Ob   = Xb;  // alias: Xb is dead after GEMM1

    prep_kernel<<<16396, 256, 0, stream>>>(queries, Wq, Wk, Wv, Wo, bq, bk, bv,
                                           Xb, Wqkv, Wob, bqkv, tab);

    gemm_qkv_rope<<<dim3(64, 24), 256, 0, stream>>>(Xb, Wqkv, bqkv, tab, Qb, Kb, Vtmp);
    repack_v<<<dim3(32, 64), 256, 0, stream>>>(Vtmp, Vt);
    attn_kernel<<<dim3(16, 64), 256, 0, stream>>>(Qb, Kb, Vt, Ob);
    gemm_bt<0><<<dim3(64, 8), 256, 0, stream>>>(Ob, Wob, bo, d_out, 8192, 1024, 1024);
}

// Round 8
// 300.282 us; speedup vs baseline: 1.0944x; 1.0040x over previous
//
#include <hip/hip_runtime.h>
#include <stdint.h>

typedef __bf16 bf16_t;
typedef __bf16 bf16x4 __attribute__((ext_vector_type(4)));
typedef __bf16 bf16x8 __attribute__((ext_vector_type(8)));
typedef float  f32x4  __attribute__((ext_vector_type(4)));

#define BB   4
#define SS   2048
#define DD   1024
#define HH   16
#define DH   64

#if __has_builtin(__builtin_amdgcn_exp2f)
#define EXP2F(x) __builtin_amdgcn_exp2f(x)
#else
#define EXP2F(x) __expf((x) * 0.6931471805599453f)
#endif

// ---------------------------------------------------------------- helpers
__device__ __forceinline__ void gload_lds16(const void* g, void* l) {
    // dest LDS addr = wave-uniform base + lane*16 (measured m104/m108)
    __builtin_amdgcn_global_load_lds(
        (__attribute__((address_space(1))) void*)(uintptr_t)g,
        (__attribute__((address_space(3))) void*)(uint32_t)(uintptr_t)l,
        16, 0, 0);
}

// ---------------------------------------------------------------- fused prep
// one launch: X fp32->bf16 (8192 blocks), 4 weights fp32->bf16 (4096),
// rope cos/sin table (4096), bias pack (12). grid = 16396.
__global__ __launch_bounds__(256) void prep_kernel(
        const float* __restrict__ queries,
        const float* __restrict__ Wq, const float* __restrict__ Wk,
        const float* __restrict__ Wv, const float* __restrict__ Wo,
        const float* __restrict__ bq, const float* __restrict__ bk,
        const float* __restrict__ bv,
        bf16_t* __restrict__ Xb, bf16_t* __restrict__ Wqkv,
        bf16_t* __restrict__ Wob, float* __restrict__ bqkv,
        float2* __restrict__ tab)
{
    const int bid = blockIdx.x, t = threadIdx.x;
    if (bid < 8192) {                       // X convert: 2097152 float4
        const int i = bid * 256 + t;
        float4 v = ((const float4*)queries)[i];
        bf16x4 o;
        o.x = (bf16_t)v.x; o.y = (bf16_t)v.y; o.z = (bf16_t)v.z; o.w = (bf16_t)v.w;
        ((bf16x4*)Xb)[i] = o;
    } else if (bid < 12288) {               // weights: 1048576 float4
        const int i = (bid - 8192) * 256 + t;
        const int which = i >> 18, p = i & 262143;
        const float* src = (which == 0) ? Wq : (which == 1) ? Wk : (which == 2) ? Wv : Wo;
        bf16_t* dst = (which < 3) ? (Wqkv + (long)which * 1048576) : Wob;
        float4 v = ((const float4*)src)[p];
        bf16x4 o;
        o.x = (bf16_t)v.x; o.y = (bf16_t)v.y; o.z = (bf16_t)v.z; o.w = (bf16_t)v.w;
        ((bf16x4*)dst)[p] = o;
    } else if (bid < 16384) {               // rope table: 2048*512 entries
        const int i = (bid - 12288) * 256 + t;
        const int s = i >> 9, pr = i & 511;
        float inv = powf(10000.0f, -(float)(2 * pr) * (1.0f / 1024.0f));
        float c, sn;
        sincosf((float)s * inv, &sn, &c);
        tab[i] = make_float2(c, sn);
    } else {                                // bias pack: 3072
        const int i = (bid - 16384) * 256 + t;
        if (i < 3072)
            bqkv[i] = (i < 1024) ? bq[i] : ((i < 2048) ? bk[i - 1024] : bv[i - 2048]);
    }
}

// ---------------------------------------------------------------- fused QKV GEMM + bias + RoPE + V-transpose
// C = X @ Wqkv^T + bqkv. Q/K cols -> rope -> Qb/Kb (bh, s, d); V cols ->
// written TRANSPOSED directly to Vt (bh, d, s) (replaces the repack_v pass:
// per V-wave h is constant and C-layout rows come in consecutive 4-token
// quads = one bf16x4 along Vt's s-axis).
// LDS chunk XOR swizzle (^(row&3)): un-swizzled fragment reads put octet
// lanes 0/2/4/6 on one bank quad (4-way, 1.58x per m136); swizzled is 2-way
// max = free. Staging coalescing unchanged (same 64B row segments).
__global__ __launch_bounds__(256, 3) void gemm_qkv_rope(
        const bf16_t* __restrict__ A, const bf16_t* __restrict__ Bm,
        const float* __restrict__ bias, const float2* __restrict__ tab,
        bf16_t* __restrict__ Qb, bf16_t* __restrict__ Kb, bf16_t* __restrict__ Vt)
{
    __shared__ __attribute__((aligned(16))) bf16_t As[128 * 32];
    __shared__ __attribute__((aligned(16))) bf16_t Bs[128 * 32];
    const int t = threadIdx.x;
    const int lane = t & 63, w = t >> 6;
    const int wm = w >> 1, wn = w & 1;
    const int l15 = lane & 15, l4 = lane >> 4;
    const int xg = l15 & 3;                  // read-side swizzle (= row&3)
    const long rowA0 = (long)blockIdx.x * 128;
    const long rowB0 = (long)blockIdx.y * 128;
    const int K = 1024;

    const f32x4 vz = {0.f, 0.f, 0.f, 0.f};
    f32x4 acc[4][4];
#pragma unroll
    for (int i = 0; i < 4; ++i)
#pragma unroll
        for (int j = 0; j < 4; ++j) acc[i][j] = vz;

    for (int kk = 0; kk < K; kk += 32) {
        __syncthreads();
#pragma unroll
        for (int i = 0; i < 2; ++i) {
            const int cb = i * 256 + w * 64;
            const int c  = cb + lane;
            const int r  = c >> 2;
            const int ko = ((c & 3) ^ (r & 3)) << 3;   // swizzled src chunk
            gload_lds16(A  + (rowA0 + r) * K + kk + ko, As + cb * 8);
            gload_lds16(Bm + (rowB0 + r) * K + kk + ko, Bs + cb * 8);
        }
        __syncthreads();
        bf16x8 af[4], bfr[4];
#pragma unroll
        for (int i = 0; i < 4; ++i)
            af[i] = *(const bf16x8*)(As + (wm * 64 + i * 16 + l15) * 32 + ((l4 ^ xg) * 8));
#pragma unroll
        for (int j = 0; j < 4; ++j)
            bfr[j] = *(const bf16x8*)(Bs + (wn * 64 + j * 16 + l15) * 32 + ((l4 ^ xg) * 8));
#pragma unroll
        for (int i = 0; i < 4; ++i)
#pragma unroll
            for (int j = 0; j < 4; ++j)
                acc[i][j] = __builtin_amdgcn_mfma_f32_16x16x32_bf16(af[i], bfr[j], acc[i][j], 0, 0, 0);
    }

    const long crow0 = rowA0 + wm * 64;
    const int  ccol0 = (int)rowB0 + wn * 64;     // global col in [0,3072), multiple of 64
    const int  part  = blockIdx.y >> 3;          // 0=Q, 1=K, 2=V
    const int  b     = (int)(crow0 >> 11);
    const int  s0    = (int)(crow0 & 2047);      // 64 rows stay in one batch

    if (part == 2) {
        const int h = (ccol0 - 2048) >> 6;       // wave-constant head
#pragma unroll
        for (int j = 0; j < 4; ++j) {
            const int d = j * 16 + l15;
            const float bb = bias[ccol0 + j * 16 + l15];
            bf16_t* dstc = Vt + ((long)(b * HH + h) * DH + d) * SS + s0;
#pragma unroll
            for (int i = 0; i < 4; ++i) {
                bf16x4 pk;
                pk.x = (bf16_t)(acc[i][j][0] + bb);
                pk.y = (bf16_t)(acc[i][j][1] + bb);
                pk.z = (bf16_t)(acc[i][j][2] + bb);
                pk.w = (bf16_t)(acc[i][j][3] + bb);
                *(bf16x4*)(dstc + i * 16 + l4 * 4) = pk;
            }
        }
    } else {
        bf16_t* dst0 = part ? Kb : Qb;
        const int h = (ccol0 & 1023) >> 6;       // this wave's 64-col strip = one head
        const int even = !(l15 & 1);
#pragma unroll
        for (int i = 0; i < 4; ++i) {
#pragma unroll
            for (int j = 0; j < 4; ++j) {
                const int col = ccol0 + j * 16 + l15;
                const float bb = bias[col];
                const int dd = j * 16 + l15;
                const float2* trow = tab + (col >> 1 & 511);
#pragma unroll
                for (int r = 0; r < 4; ++r) {
                    const int s = s0 + i * 16 + l4 * 4 + r;
                    const float val = acc[i][j][r] + bb;
                    const float par = __shfl_xor(val, 1);
                    const float2 cs = trow[s * 512];
                    const float out = even ? (val * cs.x - par * cs.y)
                                           : fmaf(val, cs.x, par * cs.y);
                    // pair-store: even lane writes {out_even, out_odd} as b32
                    const float op = __shfl_xor(out, 1);
                    if (even) {
                        union { bf16_t hh[2]; unsigned int u; } cv;
                        cv.hh[0] = (bf16_t)out; cv.hh[1] = (bf16_t)op;
                        *(unsigned int*)(dst0 + ((long)((b * HH + h) * SS + s)) * DH + dd) = cv.u;
                    }
                }
            }
        }
    }
}

// ---------------------------------------------------------------- NT GEMM (output projection)
template <int OUT_BF16>
__global__ __launch_bounds__(256, 3) void gemm_bt(
        const bf16_t* __restrict__ A, const bf16_t* __restrict__ Bm,
        const float* __restrict__ bias, void* __restrict__ Cout,
        int M, int N, int K)
{
    __shared__ __attribute__((aligned(16))) bf16_t As[128 * 32];
    __shared__ __attribute__((aligned(16))) bf16_t Bs[128 * 32];
    const int t = threadIdx.x;
    const int lane = t & 63, w = t >> 6;
    const int wm = w >> 1, wn = w & 1;
    const int l15 = lane & 15, l4 = lane >> 4;
    const int xg = l15 & 3;
    const long rowA0 = (long)blockIdx.x * 128;
    const long rowB0 = (long)blockIdx.y * 128;

    const f32x4 vz = {0.f, 0.f, 0.f, 0.f};
    f32x4 acc[4][4];
#pragma unroll
    for (int i = 0; i < 4; ++i)
#pragma unroll
        for (int j = 0; j < 4; ++j) acc[i][j] = vz;

    for (int kk = 0; kk < K; kk += 32) {
        __syncthreads();
#pragma unroll
        for (int i = 0; i < 2; ++i) {
            const int cb = i * 256 + w * 64;
            const int c  = cb + lane;
            const int r  = c >> 2;
            const int ko = ((c & 3) ^ (r & 3)) << 3;   // swizzled src chunk
            gload_lds16(A  + (rowA0 + r) * K + kk + ko, As + cb * 8);
            gload_lds16(Bm + (rowB0 + r) * K + kk + ko, Bs + cb * 8);
        }
        __syncthreads();
        bf16x8 af[4], bfr[4];
#pragma unroll
        for (int i = 0; i < 4; ++i)
            af[i] = *(const bf16x8*)(As + (wm * 64 + i * 16 + l15) * 32 + ((l4 ^ xg) * 8));
#pragma unroll
        for (int j = 0; j < 4; ++j)
            bfr[j] = *(const bf16x8*)(Bs + (wn * 64 + j * 16 + l15) * 32 + ((l4 ^ xg) * 8));
#pragma unroll
        for (int i = 0; i < 4; ++i)
#pragma unroll
            for (int j = 0; j < 4; ++j)
                acc[i][j] = __builtin_amdgcn_mfma_f32_16x16x32_bf16(af[i], bfr[j], acc[i][j], 0, 0, 0);
    }

    const long crow0 = rowA0 + wm * 64;
    const int  ccol0 = (int)rowB0 + wn * 64;
#pragma unroll
    for (int i = 0; i < 4; ++i) {
#pragma unroll
        for (int j = 0; j < 4; ++j) {
            const int col = ccol0 + j * 16 + l15;
            const float bb = bias[col];
#pragma unroll
            for (int r = 0; r < 4; ++r) {
                const long row = crow0 + i * 16 + l4 * 4 + r;
                const float v = acc[i][j][r] + bb;
                if (OUT_BF16) ((bf16_t*)Cout)[row * N + col] = (bf16_t)v;
                else          ((float*)Cout)[row * N + col]  = v;
            }
        }
    }
}

// ---------------------------------------------------------------- flash attention
// grid (16 q-tiles of 128, 64 bh). 4 waves; wave w owns q rows
// [qt*128 + w*32, +32) as TWO 16-row strips (s = 0,1).
//
// R8 = exact R6 kernel (95.5 us measured, MfmaUtil 30.6, conflicts 6.3e6,
// 4 blocks/CU). R7's dbuf traded a block/CU for DMA hiding and LOST
// (occupancy 33.7->25, 95.5->103.8): cross-block overlap at 4 blocks/CU
// already hides most of the staging latency. Do not re-add dbuf here.
__global__ __launch_bounds__(256, 4) void attn_kernel(const bf16_t* __restrict__ Qb,
                                                      const bf16_t* __restrict__ Kb,
                                                      const bf16_t* __restrict__ Vt,
                                                      bf16_t* __restrict__ Ob)
{
    __shared__ __attribute__((aligned(16))) bf16_t Ks[64 * 64];   // [key][d], swizzled
    __shared__ __attribute__((aligned(16))) bf16_t Vs[64 * 64];   // [d][key], swizzled
    __shared__ __attribute__((aligned(16))) bf16_t Ps[128 * 72];  // [q][key], pitch 72
    const int t = threadIdx.x, lane = t & 63, w = t >> 6;
    const int l15 = lane & 15, l4 = lane >> 4;
    const int xr = l15 & 7;               // read-side swizzle pattern (= row&7)
    const int qt = blockIdx.x, bh = blockIdx.y;
    const bf16_t* Qbh = Qb + (long)bh * SS * DH;
    const bf16_t* Kbh = Kb + (long)bh * SS * DH;
    const bf16_t* Vbh = Vt + (long)bh * DH * SS;

    const int qbase = qt * 128 + w * 32;
    bf16x8 qf[2][2];
#pragma unroll
    for (int s = 0; s < 2; ++s) {
        const long qrow = qbase + 16 * s + l15;
        qf[s][0] = *(const bf16x8*)(Qbh + qrow * DH + l4 * 8);
        qf[s][1] = *(const bf16x8*)(Qbh + qrow * DH + 32 + l4 * 8);
    }

    const f32x4 vz = {0.f, 0.f, 0.f, 0.f};
    f32x4 oacc[2][4];
#pragma unroll
    for (int s = 0; s < 2; ++s)
#pragma unroll
        for (int j = 0; j < 4; ++j) oacc[s][j] = vz;
    float l_sum[2] = {0.f, 0.f};

    int srow[2], scc[2];
#pragma unroll
    for (int i = 0; i < 2; ++i) {
        const int L = i * 256 + w * 64 + lane;
        srow[i] = L >> 3;
        scc[i]  = (L & 7) ^ (srow[i] & 7);
    }

    const float SC = 0.125f * 1.4426950408889634f;
    const float BI = -8.0f  * 1.4426950408889634f;

    for (int kt = 0; kt < SS / 64; ++kt) {
        __syncthreads();
        const bf16_t* Ksrc = Kbh + (long)kt * 64 * DH;
#pragma unroll
        for (int i = 0; i < 2; ++i) {
            const int cb = i * 256 + w * 64;
            gload_lds16(Ksrc + srow[i] * 64 + scc[i] * 8, Ks + cb * 8);
            gload_lds16(Vbh + (long)srow[i] * SS + kt * 64 + scc[i] * 8, Vs + cb * 8);
        }
        __syncthreads();

        // S^T = K Q^T for both strips; kf shared across strips
        f32x4 sacc[2][4];
#pragma unroll
        for (int s = 0; s < 2; ++s)
#pragma unroll
            for (int j = 0; j < 4; ++j) sacc[s][j] = vz;
#pragma unroll
        for (int j = 0; j < 4; ++j) {
            const int rk = (j * 16 + l15) * 64;
            const bf16x8 kf0 = *(const bf16x8*)(Ks + rk + ((l4 ^ xr) * 8));
            const bf16x8 kf1 = *(const bf16x8*)(Ks + rk + (((4 + l4) ^ xr) * 8));
#pragma unroll
            for (int s = 0; s < 2; ++s) {
                sacc[s][j] = __builtin_amdgcn_mfma_f32_16x16x32_bf16(kf0, qf[s][0], sacc[s][j], 0, 0, 0);
                sacc[s][j] = __builtin_amdgcn_mfma_f32_16x16x32_bf16(kf1, qf[s][1], sacc[s][j], 0, 0, 0);
            }
        }

        // p = exp2(s*SC + BI); lane holds q' = l15 (col), keys j*16 + l4*4 + r
#pragma unroll
        for (int s = 0; s < 2; ++s) {
#pragma unroll
            for (int j = 0; j < 4; ++j) {
                const float p0 = EXP2F(fmaf(sacc[s][j][0], SC, BI));
                const float p1 = EXP2F(fmaf(sacc[s][j][1], SC, BI));
                const float p2 = EXP2F(fmaf(sacc[s][j][2], SC, BI));
                const float p3 = EXP2F(fmaf(sacc[s][j][3], SC, BI));
                l_sum[s] += (p0 + p1) + (p2 + p3);
                bf16x4 pk;
                pk.x = (bf16_t)p0; pk.y = (bf16_t)p1; pk.z = (bf16_t)p2; pk.w = (bf16_t)p3;
                *(bf16x4*)(Ps + (w * 32 + 16 * s + l15) * 72 + j * 16 + l4 * 4) = pk;
            }
        }
        // no __syncthreads(): Ps rows [w*32, w*32+32) are wave-local;
        // in-wave DS ops complete in order.

        bf16x8 pf[2][2];
#pragma unroll
        for (int s = 0; s < 2; ++s) {
            pf[s][0] = *(const bf16x8*)(Ps + (w * 32 + 16 * s + l15) * 72 + l4 * 8);
            pf[s][1] = *(const bf16x8*)(Ps + (w * 32 + 16 * s + l15) * 72 + 32 + l4 * 8);
        }
#pragma unroll
        for (int j = 0; j < 4; ++j) {
            const int rv = (j * 16 + l15) * 64;
            const bf16x8 vf0 = *(const bf16x8*)(Vs + rv + ((l4 ^ xr) * 8));
            const bf16x8 vf1 = *(const bf16x8*)(Vs + rv + (((4 + l4) ^ xr) * 8));
#pragma unroll
            for (int s = 0; s < 2; ++s) {
                oacc[s][j] = __builtin_amdgcn_mfma_f32_16x16x32_bf16(pf[s][0], vf0, oacc[s][j], 0, 0, 0);
                oacc[s][j] = __builtin_amdgcn_mfma_f32_16x16x32_bf16(pf[s][1], vf1, oacc[s][j], 0, 0, 0);
            }
        }
    }

    const int b = bh >> 4, h = bh & 15;
#pragma unroll
    for (int s = 0; s < 2; ++s) {
        float lt = l_sum[s];
        lt += __shfl_xor(lt, 16);
        lt += __shfl_xor(lt, 32);
        const float inv = 1.0f / lt;
        float invr[4];
#pragma unroll
        for (int r = 0; r < 4; ++r)
            invr[r] = __shfl(inv, l4 * 4 + r);   // lane l4*4+r holds inv for q'=l4*4+r
#pragma unroll
        for (int j = 0; j < 4; ++j) {
#pragma unroll
            for (int r = 0; r < 4; ++r) {
                const int row = qbase + 16 * s + l4 * 4 + r;
                const float v = oacc[s][j][r] * invr[r];
                Ob[((long)(b * SS + row)) * DD + h * DH + j * 16 + l15] = (bf16_t)v;
            }
        }
    }
}

// ---------------------------------------------------------------- launch
extern "C" void kernel_launch(void* const* d_in, const int* in_sizes, int n_in,
                              void* d_out, int out_size, void* d_ws, size_t ws_size,
                              hipStream_t stream)
{
    const float* queries = (const float*)d_in[0];
    const float* Wq = (const float*)d_in[1];
    const float* bq = (const float*)d_in[2];
    const float* Wk = (const float*)d_in[3];
    const float* bk = (const float*)d_in[4];
    const float* Wv = (const float*)d_in[5];
    const float* bv = (const float*)d_in[6];
    const float* Wo = (const float*)d_in[7];
    const float* bo = (const float*)d_in[8];

    char* ws = (char*)d_ws;
    size_t off = 0;
    auto alloc = [&](size_t bytes) { size_t o = off; off += (bytes + 255) & ~(size_t)255; return o; };
    bf16_t* Xb   = (bf16_t*)(ws + alloc(8192u * 1024u * 2u));       // 16 MB
    bf16_t* Wqkv = (bf16_t*)(ws + alloc(3072u * 1024u * 2u));       // 6 MB
    bf16_t* Wob  = (bf16_t*)(ws + alloc(1024u * 1024u * 2u));       // 2 MB
    float*  bqkv = (float*) (ws + alloc(3072u * 4u));
    float2* tab  = (float2*)(ws + alloc(2048u * 512u * 8u));        // 8 MB
    bf16_t* Qb   = (bf16_t*)(ws + alloc(64u * 2048u * 64u * 2u));   // 16 MB
    bf16_t* Kb   = (bf16_t*)(ws + alloc(64u * 2048u * 64u * 2u));   // 16 MB
    bf16_t* Vt   = (bf16_t*)(ws + alloc(64u * 64u * 2048u * 2u));   // 16 MB
    bf16_t* Ob   = Xb;  // alias: Xb is dead after GEMM1

    prep_kernel<<<16396, 256, 0, stream>>>(queries, Wq, Wk, Wv, Wo, bq, bk, bv,
                                           Xb, Wqkv, Wob, bqkv, tab);

    gemm_qkv_rope<<<dim3(64, 24), 256, 0, stream>>>(Xb, Wqkv, bqkv, tab, Qb, Kb, Vt);
    attn_kernel<<<dim3(16, 64), 256, 0, stream>>>(Qb, Kb, Vt, Ob);
    gemm_bt<0><<<dim3(64, 8), 256, 0, stream>>>(Ob, Wob, bo, d_out, 8192, 1024, 1024);
}